// Round 1
// baseline (3338.404 us; speedup 1.0000x reference)
//
#include <hip/hip_runtime.h>

#define N_NODES  500000
#define N_EDGES  16000000
#define N_GRAPHS 5000

// workspace layout (float offsets)
#define WS_AGG   0            // N*4      = 2,000,000
#define WS_SUMS  2000000      // G*64     = 320,000
#define WS_CNT   2320000      // G        = 5,000
#define WS_W1F   2325008      // 512   (w1 folded, [j][c] layout)
#define WS_B1F   2325520      // 128
#define WS_W2F   2325648      // 8192  (w2 folded, [j][k])
#define WS_B2F   2333840      // 64
#define WS_ZERO_FLOATS 2325000

// ---------------- fold BN into weights ----------------
__global__ void k_prep(const float* __restrict__ w1, const float* __restrict__ b1,
                       const float* __restrict__ g1, const float* __restrict__ be1,
                       const float* __restrict__ m1, const float* __restrict__ v1,
                       const float* __restrict__ w2, const float* __restrict__ b2,
                       const float* __restrict__ g2, const float* __restrict__ be2,
                       const float* __restrict__ m2, const float* __restrict__ v2,
                       float* __restrict__ ws) {
    int t = threadIdx.x;  // 128 threads
    if (t < 128) {
        float s = g1[t] * rsqrtf(v1[t] + 1e-5f);
        ws[WS_B1F + t] = (b1[t] - m1[t]) * s + be1[t];
        for (int c = 0; c < 4; ++c)
            ws[WS_W1F + t * 4 + c] = w1[c * 128 + t] * s;   // transpose to [j][c]
    }
    if (t < 64) {
        float s = g2[t] * rsqrtf(v2[t] + 1e-5f);
        ws[WS_B2F + t] = (b2[t] - m2[t]) * s + be2[t];
        for (int j = 0; j < 128; ++j)
            ws[WS_W2F + j * 64 + t] = w2[j * 64 + t] * s;
    }
}

// ---------------- edge scatter-add ----------------
__global__ __launch_bounds__(256) void k_edge(const int* __restrict__ ei,
                                              const float4* __restrict__ x4,
                                              float* __restrict__ agg) {
    int e = blockIdx.x * 256 + threadIdx.x;
    if (e >= N_EDGES) return;
    int s = ei[e];
    int d = ei[N_EDGES + e];
    float4 v = x4[s];
    atomicAdd(&agg[d * 4 + 0], v.x);
    atomicAdd(&agg[d * 4 + 1], v.y);
    atomicAdd(&agg[d * 4 + 2], v.z);
    atomicAdd(&agg[d * 4 + 3], v.w);
}

// ---------------- fused node MLP + pooled accumulation ----------------
#define BLK 256
__global__ __launch_bounds__(256) void k_node(const float4* __restrict__ x4,
                                              const float4* __restrict__ agg4,
                                              const int* __restrict__ batch,
                                              const float* __restrict__ epsp,
                                              const float* __restrict__ ws,
                                              float* __restrict__ sums,
                                              float* __restrict__ cnt) {
    __shared__ float w1s[512];    // [j][c]
    __shared__ float b1s[128];
    __shared__ float w2s[8192];   // [j][k]
    __shared__ float b2s[64];
    __shared__ float stage[BLK * 17];   // pad 17 to spread banks
    __shared__ int   bsh[BLK];

    int t = threadIdx.x;

    // cooperative weight load (broadcast-read later -> conflict free)
    {
        const float4* src = (const float4*)(ws + WS_W2F);
        float4* dst = (float4*)w2s;
        #pragma unroll
        for (int i = 0; i < 8; ++i) dst[t + i * BLK] = src[t + i * BLK];
        if (t < 128) {
            ((float4*)w1s)[t] = ((const float4*)(ws + WS_W1F))[t];
            b1s[t] = ws[WS_B1F + t];
        }
        if (t < 64) b2s[t] = ws[WS_B2F + t];
    }

    int i = blockIdx.x * BLK + t;
    bool valid = i < N_NODES;
    float4 xi = valid ? x4[i]   : make_float4(0.f, 0.f, 0.f, 0.f);
    float4 ai = valid ? agg4[i] : make_float4(0.f, 0.f, 0.f, 0.f);
    int b = valid ? batch[i] : -1;
    bsh[t] = b;
    float ep = 1.0f + epsp[0];
    float hx = ep * xi.x + ai.x;
    float hy = ep * xi.y + ai.y;
    float hz = ep * xi.z + ai.z;
    float hw = ep * xi.w + ai.w;

    __syncthreads();

    float acc[64];
    #pragma unroll
    for (int k = 0; k < 64; ++k) acc[k] = b2s[k];

    for (int j = 0; j < 128; ++j) {
        float4 wr = ((const float4*)w1s)[j];
        float h1 = fmaf(hx, wr.x, fmaf(hy, wr.y, fmaf(hz, wr.z, fmaf(hw, wr.w, b1s[j]))));
        h1 = fmaxf(h1, 0.0f);
        const float4* w2row = (const float4*)&w2s[j * 64];
        #pragma unroll
        for (int k4 = 0; k4 < 16; ++k4) {
            float4 w = w2row[k4];
            acc[k4 * 4 + 0] = fmaf(h1, w.x, acc[k4 * 4 + 0]);
            acc[k4 * 4 + 1] = fmaf(h1, w.y, acc[k4 * 4 + 1]);
            acc[k4 * 4 + 2] = fmaf(h1, w.z, acc[k4 * 4 + 2]);
            acc[k4 * 4 + 3] = fmaf(h1, w.w, acc[k4 * 4 + 3]);
        }
    }
    #pragma unroll
    for (int k = 0; k < 64; ++k) acc[k] = fmaxf(acc[k], 0.0f);

    // pooling: batch is sorted -> per-block segmented scan via LDS staging
    int k16 = t & 15, q = t >> 4;
    #pragma unroll
    for (int r = 0; r < 4; ++r) {
        #pragma unroll
        for (int j = 0; j < 16; ++j) stage[t * 17 + j] = acc[r * 16 + j];
        __syncthreads();
        int base_n = q * 16;
        int cur = bsh[base_n];
        float a = 0.0f, c = 0.0f;
        for (int n = base_n; n < base_n + 16; ++n) {
            int bn = bsh[n];
            if (bn != cur) {
                if (cur >= 0) {
                    atomicAdd(&sums[cur * 64 + r * 16 + k16], a);
                    if (r == 0 && k16 == 0) atomicAdd(&cnt[cur], c);
                }
                a = 0.0f; c = 0.0f; cur = bn;
            }
            if (bn >= 0) { a += stage[n * 17 + k16]; c += 1.0f; }
        }
        if (cur >= 0) {
            atomicAdd(&sums[cur * 64 + r * 16 + k16], a);
            if (r == 0 && k16 == 0) atomicAdd(&cnt[cur], c);
        }
        __syncthreads();
    }
}

// ---------------- head: mean-pool finish + Linear(64,2) + log_softmax ----------------
__global__ __launch_bounds__(256) void k_head(const float* __restrict__ sums,
                                              const float* __restrict__ cnt,
                                              const float* __restrict__ w3,
                                              const float* __restrict__ b3,
                                              float* __restrict__ out) {
    int g = blockIdx.x * 256 + threadIdx.x;
    if (g >= N_GRAPHS) return;
    float ic = 1.0f / fmaxf(cnt[g], 1.0f);
    float l0 = b3[0], l1 = b3[1];
    #pragma unroll 8
    for (int k = 0; k < 64; ++k) {
        float p = sums[g * 64 + k] * ic;
        l0 = fmaf(p, w3[k * 2 + 0], l0);
        l1 = fmaf(p, w3[k * 2 + 1], l1);
    }
    float m = fmaxf(l0, l1);
    float lse = m + logf(expf(l0 - m) + expf(l1 - m));
    out[g * 2 + 0] = l0 - lse;
    out[g * 2 + 1] = l1 - lse;
}

extern "C" void kernel_launch(void* const* d_in, const int* in_sizes, int n_in,
                              void* d_out, int out_size, void* d_ws, size_t ws_size,
                              hipStream_t stream) {
    const float* x   = (const float*)d_in[0];
    const float* eps = (const float*)d_in[1];
    const float* w1  = (const float*)d_in[2];
    const float* b1  = (const float*)d_in[3];
    const float* g1  = (const float*)d_in[4];
    const float* be1 = (const float*)d_in[5];
    const float* m1  = (const float*)d_in[6];
    const float* v1  = (const float*)d_in[7];
    const float* w2  = (const float*)d_in[8];
    const float* b2  = (const float*)d_in[9];
    const float* g2  = (const float*)d_in[10];
    const float* be2 = (const float*)d_in[11];
    const float* m2  = (const float*)d_in[12];
    const float* v2  = (const float*)d_in[13];
    const float* w3  = (const float*)d_in[14];
    const float* b3  = (const float*)d_in[15];
    const int*   ei  = (const int*)d_in[16];
    const int*   batch = (const int*)d_in[17];

    float* ws = (float*)d_ws;

    // zero agg + sums + cnt
    hipMemsetAsync(ws, 0, (size_t)WS_ZERO_FLOATS * sizeof(float), stream);

    k_prep<<<1, 128, 0, stream>>>(w1, b1, g1, be1, m1, v1, w2, b2, g2, be2, m2, v2, ws);

    k_edge<<<(N_EDGES + 255) / 256, 256, 0, stream>>>(ei, (const float4*)x, ws + WS_AGG);

    k_node<<<(N_NODES + BLK - 1) / BLK, BLK, 0, stream>>>(
        (const float4*)x, (const float4*)(ws + WS_AGG), batch, eps, ws,
        ws + WS_SUMS, ws + WS_CNT);

    k_head<<<(N_GRAPHS + 255) / 256, 256, 0, stream>>>(
        ws + WS_SUMS, ws + WS_CNT, w3, b3, (float*)d_out);
}

// Round 2
// 781.057 us; speedup vs baseline: 4.2742x; 4.2742x over previous
//
#include <hip/hip_runtime.h>

#define N_NODES  500000
#define N_EDGES  16000000
#define N_GRAPHS 5000

// radix partition params
#define BSZ   512                  // nodes per bucket (dst>>9)
#define NB    977                  // ceil(500000/512)
#define CH    16384                // edges per chunk
#define NCH   977                  // ceil(16e6/16384)

// workspace layout (4-byte element offsets)
#define WS_AGG     0               // float, N*4   = 2,000,000
#define WS_SUMS    2000000         // float, G*64  = 320,000
#define WS_CNT     2320000         // float, G     = 5,000
#define WS_W1F     2325008         // float, 512   (16B aligned)
#define WS_B1F     2325520         // float, 128
#define WS_W2F     2325648         // float, 8192
#define WS_B2F     2333840         // float, 64
#define WS_HIST    2333904         // int,   NB*NCH = 954,529  [chunk][bin]
#define WS_BTOT    3288433         // int,   NB
#define WS_BSTART  3289410         // int,   NB+1
#define WS_CSR     3290388         // uint,  16,000,000
#define WS_TOTAL_ELEMS 19290388

// ---------------- fold BN into weights ----------------
__global__ void k_prep(const float* __restrict__ w1, const float* __restrict__ b1,
                       const float* __restrict__ g1, const float* __restrict__ be1,
                       const float* __restrict__ m1, const float* __restrict__ v1,
                       const float* __restrict__ w2, const float* __restrict__ b2,
                       const float* __restrict__ g2, const float* __restrict__ be2,
                       const float* __restrict__ m2, const float* __restrict__ v2,
                       float* __restrict__ ws) {
    int t = threadIdx.x;  // 128 threads
    if (t < 128) {
        float s = g1[t] * rsqrtf(v1[t] + 1e-5f);
        ws[WS_B1F + t] = (b1[t] - m1[t]) * s + be1[t];
        for (int c = 0; c < 4; ++c)
            ws[WS_W1F + t * 4 + c] = w1[c * 128 + t] * s;   // transpose to [j][c]
    }
    if (t < 64) {
        float s = g2[t] * rsqrtf(v2[t] + 1e-5f);
        ws[WS_B2F + t] = (b2[t] - m2[t]) * s + be2[t];
        for (int j = 0; j < 128; ++j)
            ws[WS_W2F + j * 64 + t] = w2[j * 64 + t] * s;
    }
}

// ---------------- E1: per-chunk bucket histogram ----------------
__global__ __launch_bounds__(256) void k_e1_hist(const int* __restrict__ ei,
                                                 int* __restrict__ hist) {
    __shared__ int h[NB];
    int t = threadIdx.x, blk = blockIdx.x;
    for (int i = t; i < NB; i += 256) h[i] = 0;
    __syncthreads();
    int base = blk * CH;
    int nE = min(CH, N_EDGES - base);
    for (int i = t; i < nE; i += 256) {
        int d = ei[N_EDGES + base + i];
        atomicAdd(&h[d >> 9], 1);
    }
    __syncthreads();
    for (int i = t; i < NB; i += 256) hist[blk * NB + i] = h[i];  // coalesced
}

// ---------------- E2a: per-bin exclusive scan over chunks ----------------
__global__ __launch_bounds__(256) void k_e2a_scan(int* __restrict__ hist,
                                                  int* __restrict__ binTotal) {
    __shared__ int buf[NCH];
    int t = threadIdx.x, bin = blockIdx.x;
    for (int i = t; i < NCH; i += 256) buf[i] = hist[i * NB + bin];
    __syncthreads();
    if (t == 0) {
        int run = 0;
        for (int i = 0; i < NCH; ++i) { int v = buf[i]; buf[i] = run; run += v; }
        binTotal[bin] = run;
    }
    __syncthreads();
    for (int i = t; i < NCH; i += 256) hist[i * NB + bin] = buf[i];
}

// ---------------- E2b: scan bin totals -> bucket start offsets ----------------
__global__ __launch_bounds__(256) void k_e2b_scan(const int* __restrict__ binTotal,
                                                  int* __restrict__ binStart) {
    __shared__ int buf[NB];
    int t = threadIdx.x;
    for (int i = t; i < NB; i += 256) buf[i] = binTotal[i];
    __syncthreads();
    if (t == 0) {
        int run = 0;
        for (int i = 0; i < NB; ++i) { int v = buf[i]; buf[i] = run; run += v; }
        binStart[NB] = run;   // == N_EDGES
    }
    __syncthreads();
    for (int i = t; i < NB; i += 256) binStart[i] = buf[i];
}

// ---------------- E3: place packed edges into bucket-contiguous array ----------------
__global__ __launch_bounds__(256) void k_e3_place(const int* __restrict__ ei,
                                                  const int* __restrict__ hist,
                                                  const int* __restrict__ binStart,
                                                  unsigned int* __restrict__ csr) {
    __shared__ int cursor[NB];
    int t = threadIdx.x, blk = blockIdx.x;
    for (int i = t; i < NB; i += 256)
        cursor[i] = binStart[i] + hist[blk * NB + i];   // coalesced hist read
    __syncthreads();
    int base = blk * CH;
    int nE = min(CH, N_EDGES - base);
    for (int i = t; i < nE; i += 256) {
        int e = base + i;
        int s = ei[e];
        int d = ei[N_EDGES + e];
        int bin = d >> 9;
        int pos = atomicAdd(&cursor[bin], 1);           // LDS atomic
        csr[pos] = ((unsigned int)s << 9) | (unsigned int)(d & 511);
    }
}

// ---------------- E4: per-bucket LDS aggregation + gather x ----------------
__global__ __launch_bounds__(256) void k_e4_agg(const unsigned int* __restrict__ csr,
                                                const int* __restrict__ binStart,
                                                const float4* __restrict__ x4,
                                                float* __restrict__ agg) {
    __shared__ float aggs[BSZ * 4];   // 8 KB
    int t = threadIdx.x, bin = blockIdx.x;
    for (int i = t; i < BSZ * 4; i += 256) aggs[i] = 0.0f;
    __syncthreads();
    int start = binStart[bin];
    int end   = binStart[bin + 1];
    for (int e = start + t; e < end; e += 256) {
        unsigned int v = csr[e];
        int src = (int)(v >> 9);
        int loc = (int)(v & 511u);
        float4 xv = x4[src];
        atomicAdd(&aggs[loc * 4 + 0], xv.x);
        atomicAdd(&aggs[loc * 4 + 1], xv.y);
        atomicAdd(&aggs[loc * 4 + 2], xv.z);
        atomicAdd(&aggs[loc * 4 + 3], xv.w);
    }
    __syncthreads();
    int nodeBase = bin * BSZ;
    int nvalid = min(BSZ, N_NODES - nodeBase);
    for (int i = t; i < nvalid * 4; i += 256)
        agg[nodeBase * 4 + i] = aggs[i];
}

// ---------------- fallback edge scatter (if ws too small) ----------------
__global__ __launch_bounds__(256) void k_edge(const int* __restrict__ ei,
                                              const float4* __restrict__ x4,
                                              float* __restrict__ agg) {
    int e = blockIdx.x * 256 + threadIdx.x;
    if (e >= N_EDGES) return;
    int s = ei[e];
    int d = ei[N_EDGES + e];
    float4 v = x4[s];
    atomicAdd(&agg[d * 4 + 0], v.x);
    atomicAdd(&agg[d * 4 + 1], v.y);
    atomicAdd(&agg[d * 4 + 2], v.z);
    atomicAdd(&agg[d * 4 + 3], v.w);
}

// ---------------- fused node MLP + pooled accumulation ----------------
#define BLK 256
__global__ __launch_bounds__(256) void k_node(const float4* __restrict__ x4,
                                              const float4* __restrict__ agg4,
                                              const int* __restrict__ batch,
                                              const float* __restrict__ epsp,
                                              const float* __restrict__ ws,
                                              float* __restrict__ sums,
                                              float* __restrict__ cnt) {
    __shared__ float w1s[512];    // [j][c]
    __shared__ float b1s[128];
    __shared__ float w2s[8192];   // [j][k]
    __shared__ float b2s[64];
    __shared__ float stage[BLK * 17];
    __shared__ int   bsh[BLK];

    int t = threadIdx.x;
    {
        const float4* src = (const float4*)(ws + WS_W2F);
        float4* dst = (float4*)w2s;
        #pragma unroll
        for (int i = 0; i < 8; ++i) dst[t + i * BLK] = src[t + i * BLK];
        if (t < 128) {
            ((float4*)w1s)[t] = ((const float4*)(ws + WS_W1F))[t];
            b1s[t] = ws[WS_B1F + t];
        }
        if (t < 64) b2s[t] = ws[WS_B2F + t];
    }

    int i = blockIdx.x * BLK + t;
    bool valid = i < N_NODES;
    float4 xi = valid ? x4[i]   : make_float4(0.f, 0.f, 0.f, 0.f);
    float4 ai = valid ? agg4[i] : make_float4(0.f, 0.f, 0.f, 0.f);
    int b = valid ? batch[i] : -1;
    bsh[t] = b;
    float ep = 1.0f + epsp[0];
    float hx = ep * xi.x + ai.x;
    float hy = ep * xi.y + ai.y;
    float hz = ep * xi.z + ai.z;
    float hw = ep * xi.w + ai.w;

    __syncthreads();

    float acc[64];
    #pragma unroll
    for (int k = 0; k < 64; ++k) acc[k] = b2s[k];

    for (int j = 0; j < 128; ++j) {
        float4 wr = ((const float4*)w1s)[j];
        float h1 = fmaf(hx, wr.x, fmaf(hy, wr.y, fmaf(hz, wr.z, fmaf(hw, wr.w, b1s[j]))));
        h1 = fmaxf(h1, 0.0f);
        const float4* w2row = (const float4*)&w2s[j * 64];
        #pragma unroll
        for (int k4 = 0; k4 < 16; ++k4) {
            float4 w = w2row[k4];
            acc[k4 * 4 + 0] = fmaf(h1, w.x, acc[k4 * 4 + 0]);
            acc[k4 * 4 + 1] = fmaf(h1, w.y, acc[k4 * 4 + 1]);
            acc[k4 * 4 + 2] = fmaf(h1, w.z, acc[k4 * 4 + 2]);
            acc[k4 * 4 + 3] = fmaf(h1, w.w, acc[k4 * 4 + 3]);
        }
    }
    #pragma unroll
    for (int k = 0; k < 64; ++k) acc[k] = fmaxf(acc[k], 0.0f);

    // pooling: batch sorted -> per-block segmented scan via LDS staging
    int k16 = t & 15, q = t >> 4;
    #pragma unroll
    for (int r = 0; r < 4; ++r) {
        #pragma unroll
        for (int j = 0; j < 16; ++j) stage[t * 17 + j] = acc[r * 16 + j];
        __syncthreads();
        int base_n = q * 16;
        int cur = bsh[base_n];
        float a = 0.0f, c = 0.0f;
        for (int n = base_n; n < base_n + 16; ++n) {
            int bn = bsh[n];
            if (bn != cur) {
                if (cur >= 0) {
                    atomicAdd(&sums[cur * 64 + r * 16 + k16], a);
                    if (r == 0 && k16 == 0) atomicAdd(&cnt[cur], c);
                }
                a = 0.0f; c = 0.0f; cur = bn;
            }
            if (bn >= 0) { a += stage[n * 17 + k16]; c += 1.0f; }
        }
        if (cur >= 0) {
            atomicAdd(&sums[cur * 64 + r * 16 + k16], a);
            if (r == 0 && k16 == 0) atomicAdd(&cnt[cur], c);
        }
        __syncthreads();
    }
}

// ---------------- head ----------------
__global__ __launch_bounds__(256) void k_head(const float* __restrict__ sums,
                                              const float* __restrict__ cnt,
                                              const float* __restrict__ w3,
                                              const float* __restrict__ b3,
                                              float* __restrict__ out) {
    int g = blockIdx.x * 256 + threadIdx.x;
    if (g >= N_GRAPHS) return;
    float ic = 1.0f / fmaxf(cnt[g], 1.0f);
    float l0 = b3[0], l1 = b3[1];
    #pragma unroll 8
    for (int k = 0; k < 64; ++k) {
        float p = sums[g * 64 + k] * ic;
        l0 = fmaf(p, w3[k * 2 + 0], l0);
        l1 = fmaf(p, w3[k * 2 + 1], l1);
    }
    float m = fmaxf(l0, l1);
    float lse = m + logf(expf(l0 - m) + expf(l1 - m));
    out[g * 2 + 0] = l0 - lse;
    out[g * 2 + 1] = l1 - lse;
}

extern "C" void kernel_launch(void* const* d_in, const int* in_sizes, int n_in,
                              void* d_out, int out_size, void* d_ws, size_t ws_size,
                              hipStream_t stream) {
    const float* x   = (const float*)d_in[0];
    const float* eps = (const float*)d_in[1];
    const float* w1  = (const float*)d_in[2];
    const float* b1  = (const float*)d_in[3];
    const float* g1  = (const float*)d_in[4];
    const float* be1 = (const float*)d_in[5];
    const float* m1  = (const float*)d_in[6];
    const float* v1  = (const float*)d_in[7];
    const float* w2  = (const float*)d_in[8];
    const float* b2  = (const float*)d_in[9];
    const float* g2  = (const float*)d_in[10];
    const float* be2 = (const float*)d_in[11];
    const float* m2  = (const float*)d_in[12];
    const float* v2  = (const float*)d_in[13];
    const float* w3  = (const float*)d_in[14];
    const float* b3  = (const float*)d_in[15];
    const int*   ei  = (const int*)d_in[16];
    const int*   batch = (const int*)d_in[17];

    float* ws = (float*)d_ws;
    int*   wsi = (int*)d_ws;

    k_prep<<<1, 128, 0, stream>>>(w1, b1, g1, be1, m1, v1, w2, b2, g2, be2, m2, v2, ws);

    if (ws_size >= (size_t)WS_TOTAL_ELEMS * 4) {
        // zero only sums+cnt (agg fully written by E4)
        hipMemsetAsync(ws + WS_SUMS, 0, (size_t)(320000 + 5000) * sizeof(float), stream);

        k_e1_hist<<<NCH, 256, 0, stream>>>(ei, wsi + WS_HIST);
        k_e2a_scan<<<NB, 256, 0, stream>>>(wsi + WS_HIST, wsi + WS_BTOT);
        k_e2b_scan<<<1, 256, 0, stream>>>(wsi + WS_BTOT, wsi + WS_BSTART);
        k_e3_place<<<NCH, 256, 0, stream>>>(ei, wsi + WS_HIST, wsi + WS_BSTART,
                                            (unsigned int*)(wsi + WS_CSR));
        k_e4_agg<<<NB, 256, 0, stream>>>((const unsigned int*)(wsi + WS_CSR),
                                         wsi + WS_BSTART, (const float4*)x, ws + WS_AGG);
    } else {
        // fallback: global-atomic scatter
        hipMemsetAsync(ws, 0, (size_t)(2000000 + 320000 + 5000) * sizeof(float), stream);
        k_edge<<<(N_EDGES + 255) / 256, 256, 0, stream>>>(ei, (const float4*)x, ws + WS_AGG);
    }

    k_node<<<(N_NODES + BLK - 1) / BLK, BLK, 0, stream>>>(
        (const float4*)x, (const float4*)(ws + WS_AGG), batch, eps, ws,
        ws + WS_SUMS, ws + WS_CNT);

    k_head<<<(N_GRAPHS + 255) / 256, 256, 0, stream>>>(
        ws + WS_SUMS, ws + WS_CNT, w3, b3, (float*)d_out);
}